// Round 1
// baseline (1203.975 us; speedup 1.0000x reference)
//
#include <hip/hip_runtime.h>

#define ALPHA   0.15f
#define RA      (1e-4f * 0.15f)                 // RHO*ALPHA
#define THRESH  ((1.0f + 0.01f) * 1e-4f * 0.15f) // (1+eps)*RHO*ALPHA
#define NITER   20
#define NS      8

// ---------------------------------------------------------------------------
// init: p=0, d=0 except d[seed][s] = -alpha/deg[seed]; dpk0 from (p0,d0);
// cursor=0; actFlags[0][s] from max|d0| = alpha/deg[seed_s].
// ---------------------------------------------------------------------------
__global__ void init_kernel(const float* __restrict__ deg, const int* __restrict__ seeds,
                            float* __restrict__ p, float* __restrict__ d,
                            float* __restrict__ dpk, int* __restrict__ cursor,
                            int* __restrict__ actFlags, int N) {
    int n = blockIdx.x * blockDim.x + threadIdx.x;
    if (n >= N) return;
    cursor[n] = 0;
    float dv[NS];
#pragma unroll
    for (int s = 0; s < NS; ++s) dv[s] = 0.f;
#pragma unroll
    for (int s = 0; s < NS; ++s) {
        if (seeds[s] == n) dv[s] = -ALPHA / fmaxf(deg[n], 1e-12f);
    }
#pragma unroll
    for (int s = 0; s < NS; ++s) {
        p[n * NS + s] = 0.f;
        d[n * NS + s] = dv[s];
        bool S = (0.f - dv[s]) >= RA;
        dpk[n * NS + s] = S ? -(dv[s] + RA) : 0.f;
    }
    if (n == 0) {
        for (int i = 0; i < (NITER + 1) * NS; ++i) actFlags[i] = 0;
        for (int s = 0; s < NS; ++s) {
            float m = ALPHA / fmaxf(deg[seeds[s]], 1e-12f);
            actFlags[s] = (m > THRESH) ? 1 : 0;
        }
    }
}

// ---------------------------------------------------------------------------
// exclusive scan of deg -> offs[0..N], single block of 1024 threads
// ---------------------------------------------------------------------------
#define SCAN_T 1024
__global__ void scan_kernel(const float* __restrict__ deg, int* __restrict__ offs, int N) {
    __shared__ int partial[SCAN_T];
    int t = threadIdx.x;
    int chunk = (N + SCAN_T - 1) / SCAN_T;
    int b = t * chunk;
    int e = min(b + chunk, N);
    int sum = 0;
    for (int i = b; i < e; ++i) sum += (int)deg[i];
    partial[t] = sum;
    __syncthreads();
    for (int off = 1; off < SCAN_T; off <<= 1) {
        int v = (t >= off) ? partial[t - off] : 0;
        __syncthreads();
        partial[t] += v;
        __syncthreads();
    }
    int excl = (t == 0) ? 0 : partial[t - 1];
    for (int i = b; i < e; ++i) { offs[i] = excl; excl += (int)deg[i]; }
    if (e == N) offs[N] = excl;   // threads at/after the tail all write the total
}

// ---------------------------------------------------------------------------
// scatter COO -> CSR, with per-edge weight w = v / (v*deg[col] + 1e-12)
// ---------------------------------------------------------------------------
__global__ void scatter_kernel(const int* __restrict__ row, const int* __restrict__ col,
                               const float* __restrict__ val, const float* __restrict__ deg,
                               const int* __restrict__ offs, int* __restrict__ cursor,
                               int* __restrict__ csr_col, float* __restrict__ csr_w, int E) {
    int e = blockIdx.x * blockDim.x + threadIdx.x;
    if (e >= E) return;
    int r = row[e];
    int pos = offs[r] + atomicAdd(&cursor[r], 1);
    int c = col[e];
    float v = val[e];
    csr_col[pos] = c;
    csr_w[pos] = v / (v * deg[c] + 1e-12f);
}

// ---------------------------------------------------------------------------
// one iteration: wave per row. lanes = 8 edge-groups x 8 seeds.
// tmp[r][s] = sum_e w_e * dpkIn[col_e][s]; then fused node update,
// next d_pk (double buffered), and active-flag store for iter k+1.
// ---------------------------------------------------------------------------
__global__ __launch_bounds__(256) void update_kernel(
        const int* __restrict__ offs, const int* __restrict__ csr_col,
        const float* __restrict__ csr_w, const float* __restrict__ deg,
        const int* __restrict__ actIn, int* __restrict__ actOut,
        const float* __restrict__ dpkIn, float* __restrict__ dpkOut,
        float* __restrict__ p, float* __restrict__ d, int N) {
    int wid = (blockIdx.x * blockDim.x + threadIdx.x) >> 6;
    if (wid >= N) return;
    int lane = threadIdx.x & 63;
    int s8 = lane & 7;           // seed
    int g  = lane >> 3;          // edge group 0..7
    int r = wid;

    bool act = actIn[s8] != 0;
    bool anyAct = __any(act);

    float acc = 0.f;
    if (anyAct) {
        int e0 = offs[r], e1 = offs[r + 1];
        for (int e = e0 + g; e < e1; e += 8) {
            int c = csr_col[e];
            float w = csr_w[e];
            acc += w * dpkIn[c * NS + s8];
        }
    }
    // reduce over the 8 edge-groups (lanes s8 + 8g)
    acc += __shfl_xor(acc, 8);
    acc += __shfl_xor(acc, 16);
    acc += __shfl_xor(acc, 32);

    if (lane < NS) {
        int s = lane;
        float tmp = acc;
        float dv = d[r * NS + s];
        float pv = p[r * NS + s];
        float di = 1.0f / fmaxf(deg[r], 1e-12f);
        float half = 0.5f * (1.0f - ALPHA) * di;
        bool S = (pv - dv) >= RA;
        float dpk = S ? -(dv + RA) : 0.f;
        float d_S  = (1.0f - di) * dv - RA * di - half * dpk - half * tmp;
        float d_nb = dv - half * tmp;
        float d2 = act ? (S ? d_S : d_nb) : dv;
        float p2 = act ? (S ? pv + dpk : pv) : pv;
        d[r * NS + s] = d2;
        p[r * NS + s] = p2;
        bool S2 = (p2 - d2) >= RA;
        dpkOut[r * NS + s] = S2 ? -(d2 + RA) : 0.f;
        if (act && fabsf(d2) > THRESH) actOut[s] = 1;
    }
}

// ---------------------------------------------------------------------------
// transpose p[n][s] -> out[s][n]
// ---------------------------------------------------------------------------
__global__ void transpose_kernel(const float* __restrict__ p, float* __restrict__ out, int N) {
    int n = blockIdx.x * blockDim.x + threadIdx.x;
    if (n >= N) return;
#pragma unroll
    for (int s = 0; s < NS; ++s) out[s * N + n] = p[n * NS + s];
}

extern "C" void kernel_launch(void* const* d_in, const int* in_sizes, int n_in,
                              void* d_out, int out_size, void* d_ws, size_t ws_size,
                              hipStream_t stream) {
    const int*   adj_row = (const int*)  d_in[0];
    const int*   adj_col = (const int*)  d_in[1];
    const float* adj_val = (const float*)d_in[2];
    const float* deg     = (const float*)d_in[3];
    const int*   seeds   = (const int*)  d_in[4];
    const int E = in_sizes[0];
    const int N = in_sizes[3];
    float* out = (float*)d_out;

    // workspace carve-up (256B aligned)
    char* base = (char*)d_ws;
    size_t off = 0;
    auto carve = [&](size_t bytes) -> void* {
        off = (off + 255) & ~(size_t)255;
        void* ptr = base + off;
        off += bytes;
        return ptr;
    };
    float* p      = (float*)carve((size_t)N * NS * 4);
    float* d      = (float*)carve((size_t)N * NS * 4);
    float* dpkA   = (float*)carve((size_t)N * NS * 4);
    float* dpkB   = (float*)carve((size_t)N * NS * 4);
    float* csr_w  = (float*)carve((size_t)E * 4);
    int*   offs   = (int*)  carve((size_t)(N + 1) * 4);
    int*   cursor = (int*)  carve((size_t)N * 4);
    int*   ccol   = (int*)  carve((size_t)E * 4);
    int*   actFl  = (int*)  carve((size_t)(NITER + 1) * NS * 4);

    int nb = (N + 255) / 256;
    init_kernel<<<nb, 256, 0, stream>>>(deg, seeds, p, d, dpkA, cursor, actFl, N);
    scan_kernel<<<1, SCAN_T, 0, stream>>>(deg, offs, N);
    int eb = (E + 255) / 256;
    scatter_kernel<<<eb, 256, 0, stream>>>(adj_row, adj_col, adj_val, deg, offs, cursor,
                                           ccol, csr_w, E);

    float* din  = dpkA;
    float* dout_ = dpkB;
    int ub = (N + 3) / 4;   // 4 waves (rows) per 256-thread block
    for (int k = 0; k < NITER; ++k) {
        update_kernel<<<ub, 256, 0, stream>>>(offs, ccol, csr_w, deg,
                                              actFl + k * NS, actFl + (k + 1) * NS,
                                              din, dout_, p, d, N);
        float* t = din; din = dout_; dout_ = t;
    }
    transpose_kernel<<<nb, 256, 0, stream>>>(p, out, N);
}

// Round 2
// 1030.587 us; speedup vs baseline: 1.1682x; 1.1682x over previous
//
#include <hip/hip_runtime.h>

#define ALPHA   0.15f
#define RA      (1e-4f * 0.15f)                  // RHO*ALPHA
#define THRESH  ((1.0f + 0.01f) * 1e-4f * 0.15f) // (1+eps)*RHO*ALPHA
#define NITER   20
#define NS      8

// ---------------------------------------------------------------------------
// init: p=0, d=0 except d[seed][s] = -alpha/deg[seed]; dpk0 from (p0,d0);
// cursor=0; actFlags[0][s] from max|d0| = alpha/deg[seed_s].
// ---------------------------------------------------------------------------
__global__ void init_kernel(const float* __restrict__ deg, const int* __restrict__ seeds,
                            float* __restrict__ p, float* __restrict__ d,
                            float* __restrict__ dpk, int* __restrict__ cursor,
                            int* __restrict__ actFlags, int N) {
    int n = blockIdx.x * blockDim.x + threadIdx.x;
    if (n >= N) return;
    cursor[n] = 0;
    float dv[NS];
#pragma unroll
    for (int s = 0; s < NS; ++s) dv[s] = 0.f;
#pragma unroll
    for (int s = 0; s < NS; ++s) {
        if (seeds[s] == n) dv[s] = -ALPHA / fmaxf(deg[n], 1e-12f);
    }
#pragma unroll
    for (int s = 0; s < NS; ++s) {
        p[n * NS + s] = 0.f;
        d[n * NS + s] = dv[s];
        bool S = (0.f - dv[s]) >= RA;
        dpk[n * NS + s] = S ? -(dv[s] + RA) : 0.f;
    }
    if (n == 0) {
        for (int i = 0; i < (NITER + 1) * NS; ++i) actFlags[i] = 0;
        for (int s = 0; s < NS; ++s) {
            float m = ALPHA / fmaxf(deg[seeds[s]], 1e-12f);
            actFlags[s] = (m > THRESH) ? 1 : 0;
        }
    }
}

// ---------------------------------------------------------------------------
// parallel exclusive scan of deg -> offs[0..N], three tiny kernels
// ---------------------------------------------------------------------------
__global__ void block_sum_kernel(const float* __restrict__ deg, int* __restrict__ blockSums, int N) {
    int i = blockIdx.x * 256 + threadIdx.x;
    int v = (i < N) ? (int)deg[i] : 0;
#pragma unroll
    for (int o = 1; o < 64; o <<= 1) v += __shfl_xor(v, o);
    __shared__ int ws[4];
    if ((threadIdx.x & 63) == 0) ws[threadIdx.x >> 6] = v;
    __syncthreads();
    if (threadIdx.x == 0) blockSums[blockIdx.x] = ws[0] + ws[1] + ws[2] + ws[3];
}

__global__ void scan_sums_kernel(const int* __restrict__ blockSums, int* __restrict__ blockOffs, int nB) {
    __shared__ int buf[1024];
    int t = threadIdx.x;
    int v = (t < nB) ? blockSums[t] : 0;
    buf[t] = v;
    __syncthreads();
    for (int o = 1; o < 1024; o <<= 1) {
        int u = (t >= o) ? buf[t - o] : 0;
        __syncthreads();
        buf[t] += u;
        __syncthreads();
    }
    if (t < nB) blockOffs[t] = buf[t] - v;  // exclusive
}

__global__ void write_offs_kernel(const float* __restrict__ deg, const int* __restrict__ blockOffs,
                                  int* __restrict__ offs, int N, int E) {
    int t = threadIdx.x;
    int i = blockIdx.x * 256 + t;
    int v = (i < N) ? (int)deg[i] : 0;
    __shared__ int buf[256];
    buf[t] = v;
    __syncthreads();
    for (int o = 1; o < 256; o <<= 1) {
        int u = (t >= o) ? buf[t - o] : 0;
        __syncthreads();
        buf[t] += u;
        __syncthreads();
    }
    int excl = buf[t] - v;
    if (i < N) offs[i] = blockOffs[blockIdx.x] + excl;
    if (i == 0) offs[N] = E;   // sum(deg) == E by construction (deg = bincount(row))
}

// ---------------------------------------------------------------------------
// scatter COO -> CSR; packed edge record {col*NS, bits(w)}, w = v/(v*deg[col]+1e-12)
// ---------------------------------------------------------------------------
__global__ void scatter_kernel(const int* __restrict__ row, const int* __restrict__ col,
                               const float* __restrict__ val, const float* __restrict__ deg,
                               const int* __restrict__ offs, int* __restrict__ cursor,
                               int2* __restrict__ cw, int E) {
    int e = blockIdx.x * blockDim.x + threadIdx.x;
    if (e >= E) return;
    int r = row[e];
    int pos = offs[r] + atomicAdd(&cursor[r], 1);
    int c = col[e];
    float v = val[e];
    float w = v / (v * deg[c] + 1e-12f);
    cw[pos] = make_int2(c * NS, __float_as_int(w));
}

// ---------------------------------------------------------------------------
// one iteration: wave per row. lanes = 8 edge-groups x 8 seeds.
// tmp[r][s] = sum_e w_e * dpkIn[col_e][s]; then fused node update,
// next d_pk (double buffered), and active-flag store for iter k+1.
// On the last iteration, writes out[s*N+r] directly and skips dead stores.
// ---------------------------------------------------------------------------
__global__ __launch_bounds__(256) void update_kernel(
        const int* __restrict__ offs, const int2* __restrict__ cw,
        const float* __restrict__ deg,
        const int* __restrict__ actIn, int* __restrict__ actOut,
        const float* __restrict__ dpkIn, float* __restrict__ dpkOut,
        float* __restrict__ p, float* __restrict__ d,
        float* __restrict__ outp, int last, int N) {
    int wid = (blockIdx.x * blockDim.x + threadIdx.x) >> 6;
    if (wid >= N) return;
    int lane = threadIdx.x & 63;
    int s8 = lane & 7;           // seed
    int g  = lane >> 3;          // edge group 0..7
    int r = wid;

    bool act = actIn[s8] != 0;
    bool anyAct = __any(act);

    float acc = 0.f;
    if (anyAct) {
        int e0 = offs[r], e1 = offs[r + 1];
        for (int e = e0 + g; e < e1; e += 8) {
            int2 cwv = cw[e];
            acc += __int_as_float(cwv.y) * dpkIn[cwv.x + s8];
        }
    }
    // reduce over the 8 edge-groups (lanes s8 + 8g)
    acc += __shfl_xor(acc, 8);
    acc += __shfl_xor(acc, 16);
    acc += __shfl_xor(acc, 32);

    if (lane < NS) {
        int s = lane;
        float tmp = acc;
        float dv = d[r * NS + s];
        float pv = p[r * NS + s];
        float di = 1.0f / fmaxf(deg[r], 1e-12f);
        float half = 0.5f * (1.0f - ALPHA) * di;
        bool S = (pv - dv) >= RA;
        float dpk = S ? -(dv + RA) : 0.f;
        float d_S  = (1.0f - di) * dv - RA * di - half * dpk - half * tmp;
        float d_nb = dv - half * tmp;
        float d2 = act ? (S ? d_S : d_nb) : dv;
        float p2 = act ? (S ? pv + dpk : pv) : pv;
        if (!last) {
            d[r * NS + s] = d2;
            p[r * NS + s] = p2;
            bool S2 = (p2 - d2) >= RA;
            dpkOut[r * NS + s] = S2 ? -(d2 + RA) : 0.f;
            if (act && fabsf(d2) > THRESH) actOut[s] = 1;
        } else {
            outp[s * N + r] = p2;
        }
    }
}

extern "C" void kernel_launch(void* const* d_in, const int* in_sizes, int n_in,
                              void* d_out, int out_size, void* d_ws, size_t ws_size,
                              hipStream_t stream) {
    const int*   adj_row = (const int*)  d_in[0];
    const int*   adj_col = (const int*)  d_in[1];
    const float* adj_val = (const float*)d_in[2];
    const float* deg     = (const float*)d_in[3];
    const int*   seeds   = (const int*)  d_in[4];
    const int E = in_sizes[0];
    const int N = in_sizes[3];
    float* out = (float*)d_out;

    // workspace carve-up (256B aligned)
    char* base = (char*)d_ws;
    size_t off = 0;
    auto carve = [&](size_t bytes) -> void* {
        off = (off + 255) & ~(size_t)255;
        void* ptr = base + off;
        off += bytes;
        return ptr;
    };
    float* p       = (float*)carve((size_t)N * NS * 4);
    float* d       = (float*)carve((size_t)N * NS * 4);
    float* dpkA    = (float*)carve((size_t)N * NS * 4);
    float* dpkB    = (float*)carve((size_t)N * NS * 4);
    int2*  cw      = (int2*) carve((size_t)E * 8);
    int*   offs    = (int*)  carve((size_t)(N + 1) * 4);
    int*   cursor  = (int*)  carve((size_t)N * 4);
    int*   bsums   = (int*)  carve((size_t)1024 * 4);
    int*   boffs   = (int*)  carve((size_t)1024 * 4);
    int*   actFl   = (int*)  carve((size_t)(NITER + 1) * NS * 4);

    int nb = (N + 255) / 256;      // 391 blocks
    init_kernel<<<nb, 256, 0, stream>>>(deg, seeds, p, d, dpkA, cursor, actFl, N);
    block_sum_kernel<<<nb, 256, 0, stream>>>(deg, bsums, N);
    scan_sums_kernel<<<1, 1024, 0, stream>>>(bsums, boffs, nb);
    write_offs_kernel<<<nb, 256, 0, stream>>>(deg, boffs, offs, N, E);
    int eb = (E + 255) / 256;
    scatter_kernel<<<eb, 256, 0, stream>>>(adj_row, adj_col, adj_val, deg, offs, cursor,
                                           cw, E);

    float* din   = dpkA;
    float* dout_ = dpkB;
    int ub = (N + 3) / 4;   // 4 waves (rows) per 256-thread block
    for (int k = 0; k < NITER; ++k) {
        int last = (k == NITER - 1) ? 1 : 0;
        update_kernel<<<ub, 256, 0, stream>>>(offs, cw, deg,
                                              actFl + k * NS, actFl + (k + 1) * NS,
                                              din, dout_, p, d, out, last, N);
        float* t = din; din = dout_; dout_ = t;
    }
}